// Round 8
// baseline (149.614 us; speedup 1.0000x reference)
//
#include <hip/hip_runtime.h>

#define IN_F 8192
#define OUT_F 8192
#define BLOCK 256
#define KPT (IN_F / 4 / BLOCK)   // 8 float4 per thread

typedef float v4f __attribute__((ext_vector_type(4)));

// ---- Kernel A: masked GEMV + LIF (pure read stream of syn) ----
__global__ __launch_bounds__(BLOCK) void snn_gemv_kernel(
    const float* __restrict__ x,        // [IN_F]
    const float* __restrict__ syn,      // [OUT_F, IN_F]
    const float* __restrict__ mp,       // [OUT_F]
    const float* __restrict__ at,       // [OUT_F]
    float* __restrict__ spikes_out,     // [OUT_F]
    float* __restrict__ vmem_out,       // [OUT_F]
    float* __restrict__ thr_out)        // [OUT_F]
{
    const int o   = blockIdx.x;
    const int tid = threadIdx.x;

    const v4f* __restrict__ syn4 = reinterpret_cast<const v4f*>(syn + (size_t)o * IN_F);
    const v4f* __restrict__ x4   = reinterpret_cast<const v4f*>(x);

    float partial = 0.0f;
    #pragma unroll
    for (int k = 0; k < KPT; ++k) {
        const int i = tid + k * BLOCK;
        v4f s  = syn4[i];
        v4f xv = x4[i];
        partial += (s.x > 50.0f ? xv.x : 0.0f);
        partial += (s.y > 50.0f ? xv.y : 0.0f);
        partial += (s.z > 50.0f ? xv.z : 0.0f);
        partial += (s.w > 50.0f ? xv.w : 0.0f);
    }

    #pragma unroll
    for (int off = 32; off > 0; off >>= 1)
        partial += __shfl_down(partial, off, 64);

    __shared__ float wsum[BLOCK / 64];
    if ((tid & 63) == 0) wsum[tid >> 6] = partial;
    __syncthreads();

    if (tid == 0) {
        float cur = wsum[0] + wsum[1] + wsum[2] + wsum[3];
        float v   = mp[o] * 0.8f + cur;
        float a   = at[o];
        float sp  = (v >= a) ? 1.0f : 0.0f;
        spikes_out[o] = sp;
        vmem_out[o]   = v * (1.0f - sp) * 0.2f;
        thr_out[o]    = fminf(fmaxf(a + (sp - 0.05f) * 0.1f, 0.5f), 10.0f);
    }
}

// ---- Kernel B: trace update (copy-shaped 1R:1W stream) ----
// Block per row: spike is ONE wave-uniform scalar load (broadcast), x is
// L1-resident, trace is a clean streaming read, out a clean streaming write.
__global__ __launch_bounds__(BLOCK) void snn_trace_kernel(
    const float* __restrict__ x,          // [IN_F]
    const float* __restrict__ trace,      // [OUT_F, IN_F]
    const float* __restrict__ spikes,     // [OUT_F]
    float* __restrict__ trace_out)        // [OUT_F, IN_F]
{
    const int o   = blockIdx.x;
    const int tid = threadIdx.x;

    const float sp3 = spikes[o] * 3.0f;   // wave-uniform scalar
    const v4f* __restrict__ tr4 = reinterpret_cast<const v4f*>(trace + (size_t)o * IN_F);
    const v4f* __restrict__ x4  = reinterpret_cast<const v4f*>(x);
    v4f* __restrict__ out4      = reinterpret_cast<v4f*>(trace_out + (size_t)o * IN_F);

    #pragma unroll
    for (int k = 0; k < KPT; ++k) {
        const int i = tid + k * BLOCK;
        v4f t  = tr4[i];
        v4f xv = x4[i];
        v4f r;
        r.x = fminf(fmaxf(t.x * 0.7f + sp3 * xv.x, 0.0f), 10.0f);
        r.y = fminf(fmaxf(t.y * 0.7f + sp3 * xv.y, 0.0f), 10.0f);
        r.z = fminf(fmaxf(t.z * 0.7f + sp3 * xv.z, 0.0f), 10.0f);
        r.w = fminf(fmaxf(t.w * 0.7f + sp3 * xv.w, 0.0f), 10.0f);
        out4[i] = r;
    }
}

extern "C" void kernel_launch(void* const* d_in, const int* in_sizes, int n_in,
                              void* d_out, int out_size, void* d_ws, size_t ws_size,
                              hipStream_t stream) {
    const float* x     = (const float*)d_in[0];  // spike_input [8192]
    const float* syn   = (const float*)d_in[1];  // synapse_states [8192,8192]
    const float* mp    = (const float*)d_in[2];  // membrane_potential [8192]
    const float* at    = (const float*)d_in[3];  // adaptive_threshold [8192]
    const float* trace = (const float*)d_in[4];  // eligibility_trace [8192,8192]

    float* out        = (float*)d_out;
    float* spikes_out = out;                                            // [8192]
    float* vmem_out   = out + OUT_F;                                    // [8192]
    float* trace_out  = out + 2 * (size_t)OUT_F;                        // [8192*8192]
    float* thr_out    = out + 2 * (size_t)OUT_F + (size_t)OUT_F * IN_F; // [8192]

    snn_gemv_kernel<<<OUT_F, BLOCK, 0, stream>>>(
        x, syn, mp, at, spikes_out, vmem_out, thr_out);

    snn_trace_kernel<<<OUT_F, BLOCK, 0, stream>>>(
        x, trace, spikes_out, trace_out);
}

// Round 9
// 141.268 us; speedup vs baseline: 1.0591x; 1.0591x over previous
//
#include <hip/hip_runtime.h>

#define IN_F 8192
#define OUT_F 8192
#define BLOCK 1024
#define NWAVE (BLOCK / 64)          // 16 waves
#define KPT (IN_F / 4 / BLOCK)      // 2 float4 per thread per stream

typedef float v4f __attribute__((ext_vector_type(4)));

// One row per 1024-thread block (16 waves). Full 32-waves/CU occupancy:
// more blocks-in-different-phases per CU -> steadier HBM mix, better
// latency hiding around the per-row reduce barrier.
__global__ __launch_bounds__(BLOCK) void snn_fused_kernel(
    const float* __restrict__ x,        // [IN_F] spike_input
    const float* __restrict__ syn,      // [OUT_F, IN_F] synapse_states
    const float* __restrict__ mp,       // [OUT_F] membrane_potential
    const float* __restrict__ at,       // [OUT_F] adaptive_threshold
    const float* __restrict__ trace,    // [OUT_F, IN_F] eligibility_trace
    float* __restrict__ spikes_out,     // [OUT_F]
    float* __restrict__ vmem_out,       // [OUT_F]
    float* __restrict__ trace_out,      // [OUT_F, IN_F]
    float* __restrict__ thr_out)        // [OUT_F]
{
    const int o   = blockIdx.x;
    const int tid = threadIdx.x;

    const v4f* __restrict__ syn4 = reinterpret_cast<const v4f*>(syn + (size_t)o * IN_F);
    const v4f* __restrict__ tr4  = reinterpret_cast<const v4f*>(trace + (size_t)o * IN_F);
    const v4f* __restrict__ x4   = reinterpret_cast<const v4f*>(x);

    // ---- phase 1: masked row-sum  current = sum_i (syn[o,i] > 50) * x[i]
    v4f s[KPT], xv[KPT];
    #pragma unroll
    for (int k = 0; k < KPT; ++k) {
        const int i = tid + k * BLOCK;
        s[k]  = syn4[i];
        xv[k] = x4[i];
    }

    float partial = 0.0f;
    #pragma unroll
    for (int k = 0; k < KPT; ++k) {
        partial += (s[k].x > 50.0f ? xv[k].x : 0.0f);
        partial += (s[k].y > 50.0f ? xv[k].y : 0.0f);
        partial += (s[k].z > 50.0f ? xv[k].z : 0.0f);
        partial += (s[k].w > 50.0f ? xv[k].w : 0.0f);
    }
    #pragma unroll
    for (int off = 32; off > 0; off >>= 1)
        partial += __shfl_down(partial, off, 64);

    __shared__ float wsum[NWAVE];
    if ((tid & 63) == 0) wsum[tid >> 6] = partial;
    __syncthreads();                      // the only barrier

    // all threads sum the 16 partials (64 B LDS broadcast reads)
    float cur = 0.0f;
    #pragma unroll
    for (int w = 0; w < NWAVE; ++w) cur += wsum[w];

    const float v  = mp[o] * 0.8f + cur;
    const float a  = at[o];
    const float sp = (v >= a) ? 1.0f : 0.0f;
    if (tid == 0) {
        spikes_out[o] = sp;
        vmem_out[o]   = v * (1.0f - sp) * 0.2f;
        thr_out[o]    = fminf(fmaxf(a + (sp - 0.05f) * 0.1f, 0.5f), 10.0f);
    }

    // ---- phase 2: trace update  clip(0.7*t + 3*sp*x, 0, 10)
    const float sp3 = sp * 3.0f;
    v4f* out4 = reinterpret_cast<v4f*>(trace_out + (size_t)o * IN_F);
    #pragma unroll
    for (int k = 0; k < KPT; ++k) {
        const int i = tid + k * BLOCK;
        v4f t = tr4[i];
        v4f r;
        r.x = fminf(fmaxf(t.x * 0.7f + sp3 * xv[k].x, 0.0f), 10.0f);
        r.y = fminf(fmaxf(t.y * 0.7f + sp3 * xv[k].y, 0.0f), 10.0f);
        r.z = fminf(fmaxf(t.z * 0.7f + sp3 * xv[k].z, 0.0f), 10.0f);
        r.w = fminf(fmaxf(t.w * 0.7f + sp3 * xv[k].w, 0.0f), 10.0f);
        out4[i] = r;
    }
}

extern "C" void kernel_launch(void* const* d_in, const int* in_sizes, int n_in,
                              void* d_out, int out_size, void* d_ws, size_t ws_size,
                              hipStream_t stream) {
    const float* x     = (const float*)d_in[0];  // spike_input [8192]
    const float* syn   = (const float*)d_in[1];  // synapse_states [8192,8192]
    const float* mp    = (const float*)d_in[2];  // membrane_potential [8192]
    const float* at    = (const float*)d_in[3];  // adaptive_threshold [8192]
    const float* trace = (const float*)d_in[4];  // eligibility_trace [8192,8192]

    float* out        = (float*)d_out;
    float* spikes_out = out;                                            // [8192]
    float* vmem_out   = out + OUT_F;                                    // [8192]
    float* trace_out  = out + 2 * (size_t)OUT_F;                        // [8192*8192]
    float* thr_out    = out + 2 * (size_t)OUT_F + (size_t)OUT_F * IN_F; // [8192]

    snn_fused_kernel<<<OUT_F, BLOCK, 0, stream>>>(
        x, syn, mp, at, trace, spikes_out, vmem_out, trace_out, thr_out);
}